// Round 1
// 163.210 us; speedup vs baseline: 1.0092x; 1.0092x over previous
//
#include <hip/hip_runtime.h>
#include <cstdint>
#include <cstddef>

// Problem constants
#define B_    128   // batch
#define C_    32    // in channels
#define O_    64    // out channels
#define H_    34    // input H=W (34 = 32+2)
#define NPOS  1024  // 32*32 spatial positions
#define K9    9     // 3x3 taps
#define BC    (B_ * C_)   // 4096
#define BO    (B_ * O_)   // 8192

typedef __bf16 v8bf __attribute__((ext_vector_type(8)));
typedef float  v4f  __attribute__((ext_vector_type(4)));
typedef float  f4a  __attribute__((ext_vector_type(4)));              // 16-B aligned float4
typedef unsigned short u16x8 __attribute__((ext_vector_type(8)));     // 16-B ushort8

__device__ __forceinline__ unsigned short f2bf(float f) {
    union { float f; unsigned int u; } v; v.f = f;
    unsigned int u = v.u;
    return (unsigned short)((u + 0x7FFFu + ((u >> 16) & 1u)) >> 16);
}
__device__ __forceinline__ float bf2f(unsigned short s) {
    union { unsigned int u; float f; } v; v.u = ((unsigned int)s) << 16;
    return v.f;
}

// ---------------------------------------------------------------------------
// Pass 1 (v2): repack x (fp32 [b][c][34][34]) -> x2 (bf16 [h][w][b][c]).
// Block = (b-pair, h-pair). Reading h-pairs gives 272-B contiguous runs per
// (b,c) (85% sector efficiency vs 71% for single 136-B rows, and the
// over-fetched sector is consumed in-block instead of discarded cross-XCD).
// float2 loads, ushort2 stores; LDS tile transposed to [hh][w][b*32+c] so the
// x2-write phase reads contiguous shorts (2-way banks = free).
// ---------------------------------------------------------------------------
__global__ __launch_bounds__(256) void repack_x(const float* __restrict__ x,
                                                unsigned short* __restrict__ x2) {
    const int bq = blockIdx.x / 17;      // b-pair 0..63
    const int hp = blockIdx.x % 17;      // h-pair 0..16
    const int b0 = bq * 2;
    const int h0 = hp * 2;
    __shared__ unsigned short tile[2][H_][66];   // [hh][w][bb*32+c] (+2 pad)
    const int t = threadIdx.x;

    // phase 1: 2 bb x 32 c x 34 float2 (= rows h0,h0+1 back-to-back, 68 floats)
    for (int e = t; e < 2176; e += 256) {
        const int bb  = e / 1088;
        const int rem = e % 1088;
        const int c   = rem / 34;
        const int wp  = rem % 34;        // float2 index within the 68-float run
        const float2 v = *(const float2*)(x +
            ((size_t)((b0 + bb) * C_ + c) * H_ + h0) * H_ + wp * 2);
        const int hh = (wp >= 17) ? 1 : 0;
        const int w  = wp * 2 - hh * 34;
        const int idx = bb * 32 + c;
        tile[hh][w][idx]     = f2bf(v.x);
        tile[hh][w + 1][idx] = f2bf(v.y);
    }
    __syncthreads();

    // phase 2: write x2 rows; lane writes ushort2 (contiguous b*32+c pairs)
    for (int e = t; e < 2176; e += 256) {
        const int hh  = e / 1088;
        const int rem = e % 1088;
        const int w   = rem >> 5;
        const int i2  = rem & 31;
        ushort2 pk;
        pk.x = tile[hh][w][i2 * 2];
        pk.y = tile[hh][w][i2 * 2 + 1];
        *(ushort2*)(x2 + (size_t)((h0 + hh) * H_ + w) * BC + bq * 64 + i2 * 2) = pk;
    }
}

// ---------------------------------------------------------------------------
// Main (fused): block = (i, j-quarter of 4, o-quarter of 16).  [UNCHANGED]
// Weight slice per p = contiguous 144 B (4 j x 9 k) -> aligned dwordx4 staging.
// LDS Wl is XOR-swizzled: element (d=jj*9+k, pl=o_l*32+c) lives at
//   d*512 + ((pl>>3) ^ ((d>>2)&7))*8 + (pl&7)
// K-loop: per kh, the 6 distinct (w) x2 row-fragments are loaded ONCE into
// registers (12 independent 1 KB wave-loads) and reused across (kw,jj).
// Output: ws bf16 [pos][o][b] (bias deferred to transpose_out).
// ---------------------------------------------------------------------------
__global__ __launch_bounds__(256, 4) void lc_fused(const unsigned short* __restrict__ x2,
                                                   const float* __restrict__ weight,
                                                   unsigned short* __restrict__ ws) {
    __shared__ __align__(16) unsigned short Wl[36 * 512];  // 36,864 B

    const int bid = blockIdx.x;
    const int jq = bid & 7;            // j-quarter -> XCD id (round-robin bid%8)
    const int i  = (bid >> 3) & 31;
    const int oq = bid >> 8;           // o-quarter (16 o's)
    const int j0 = jq * 4;
    const int o0 = oq * 16;
    const int posbase = i * 32 + j0;   // multiple of 4 -> weight runs 16-B aligned
    const int t = threadIdx.x;

    // ---- stage weights: 512 p x 36 floats (contiguous per p), dwordx4 ----
    const float* wbase = weight + ((size_t)(o0 * C_) * NPOS + posbase) * K9;
#pragma unroll
    for (int r = 0; r < 18; ++r) {
        const int idx = r * 256 + t;          // 0..4607
        const int pl = idx / 9;               // p_local 0..511
        const int d4 = idx % 9;               // dwordx4 index 0..8
        const f4a v = *(const f4a*)(wbase + (size_t)pl * (NPOS * K9) + d4 * 4);
        const int sw = ((pl >> 3) ^ (d4 & 7)) * 8 + (pl & 7);  // swizzled column
#pragma unroll
        for (int u = 0; u < 4; ++u)
            Wl[(d4 * 4 + u) * 512 + sw] = f2bf(v[u]);
    }
    __syncthreads();

    const int wv = t >> 6;      // wave -> b-band [wv*32, wv*32+32)
    const int l  = t & 63;
    const int lm = l & 15;      // o_local (B n-index) / A m-index
    const int q  = l >> 4;

    v4f acc[4][2];              // [jj][mt]
#pragma unroll
    for (int a = 0; a < 4; ++a)
#pragma unroll
        for (int m = 0; m < 2; ++m) acc[a][m] = (v4f){0.f, 0.f, 0.f, 0.f};

#pragma unroll
    for (int kh = 0; kh < 3; ++kh) {
        // load the 6 distinct x2 row-fragments for this kh once
        v8bf ax[6][2];
        const int rowbase = (i + kh) * H_ + j0;
#pragma unroll
        for (int w6 = 0; w6 < 6; ++w6) {
            const unsigned short* xrow = x2 + (size_t)(rowbase + w6) * BC;
            ax[w6][0] = *(const v8bf*)(xrow + (wv * 32 + lm) * C_ + q * 8);
            ax[w6][1] = *(const v8bf*)(xrow + (wv * 32 + 16 + lm) * C_ + q * 8);
        }
#pragma unroll
        for (int kw = 0; kw < 3; ++kw) {
            const int tap = kh * 3 + kw;
#pragma unroll
            for (int jj = 0; jj < 4; ++jj) {
                const int jk = jj * K9 + tap;
                const int g  = ((lm * 4 + q) ^ ((jk >> 2) & 7)) * 8;
                const v8bf bfr = *(const v8bf*)&Wl[jk * 512 + g];
                acc[jj][0] = __builtin_amdgcn_mfma_f32_16x16x32_bf16(
                    ax[kw + jj][0], bfr, acc[jj][0], 0, 0, 0);
                acc[jj][1] = __builtin_amdgcn_mfma_f32_16x16x32_bf16(
                    ax[kw + jj][1], bfr, acc[jj][1], 0, 0, 0);
            }
        }
    }

    // ---- epilogue: D col(lane&15)=o_local, row(q*4+r)=b_local ----
#pragma unroll
    for (int jj = 0; jj < 4; ++jj) {
        const int pos = posbase + jj;
        unsigned short* wp = ws + (size_t)pos * BO + (o0 + lm) * B_;
#pragma unroll
        for (int mt = 0; mt < 2; ++mt) {
            const int b = wv * 32 + mt * 16 + q * 4;
            ushort4 pk;
            pk.x = f2bf(acc[jj][mt][0]);
            pk.y = f2bf(acc[jj][mt][1]);
            pk.z = f2bf(acc[jj][mt][2]);
            pk.w = f2bf(acc[jj][mt][3]);
            *(ushort4*)(wp + b) = pk;
        }
    }
}

// ---------------------------------------------------------------------------
// Fallback (no workspace): per-pos kernel gathering straight from fp32.
// ---------------------------------------------------------------------------
__global__ __launch_bounds__(256) void lc_fallback(const float* __restrict__ x,
                                                   const float* __restrict__ weight,
                                                   const float* __restrict__ bias,
                                                   float* __restrict__ out) {
    const int pos = blockIdx.x;
    const int i = pos >> 5, j = pos & 31;
    const int t  = threadIdx.x;
    const int wv = t >> 6;
    const int l  = t & 63;
    const int lm = l & 15;
    const int q  = l >> 4;

    float bv[4];
#pragma unroll
    for (int nt = 0; nt < 4; ++nt)
        bv[nt] = bias[(size_t)(nt * 16 + lm) * NPOS + pos];

    v4f acc[2][4];
#pragma unroll
    for (int a = 0; a < 2; ++a)
#pragma unroll
        for (int n = 0; n < 4; ++n) acc[a][n] = (v4f){0.f, 0.f, 0.f, 0.f};

    for (int k = 0; k < K9; ++k) {
        const int kh = k / 3, kw = k % 3;
        v8bf af[2], bfr[4];
#pragma unroll
        for (int mt = 0; mt < 2; ++mt) {
            const int b = wv * 32 + mt * 16 + lm;
            union { v8bf v; unsigned short s[8]; } u;
#pragma unroll
            for (int cc = 0; cc < 8; ++cc)
                u.s[cc] = f2bf(x[(((size_t)b * C_ + q * 8 + cc) * H_ + (i + kh)) * H_ + (j + kw)]);
            af[mt] = u.v;
        }
#pragma unroll
        for (int nt = 0; nt < 4; ++nt) {
            union { v8bf v; unsigned short s[8]; } u;
#pragma unroll
            for (int cc = 0; cc < 8; ++cc) {
                const int p = (nt * 16 + lm) * C_ + q * 8 + cc;
                u.s[cc] = f2bf(weight[((size_t)p * NPOS + pos) * K9 + k]);
            }
            bfr[nt] = u.v;
        }
#pragma unroll
        for (int mt = 0; mt < 2; ++mt)
#pragma unroll
            for (int nt = 0; nt < 4; ++nt)
                acc[mt][nt] = __builtin_amdgcn_mfma_f32_16x16x32_bf16(
                    af[mt], bfr[nt], acc[mt][nt], 0, 0, 0);
    }
#pragma unroll
    for (int mt = 0; mt < 2; ++mt)
#pragma unroll
        for (int nt = 0; nt < 4; ++nt) {
            const int o = nt * 16 + lm;
#pragma unroll
            for (int r = 0; r < 4; ++r) {
                const int b = wv * 32 + mt * 16 + q * 4 + r;
                out[(size_t)(b * O_ + o) * NPOS + pos] = acc[mt][nt][r] + bv[nt];
            }
        }
}

// ---------------------------------------------------------------------------
// Pass 3 (v2): ws bf16 [pos][o][b] -> out fp32 [b][o][pos], + bias[o][pos].
// Block = (o, pos-tile of 64); fp32 LDS tile [64][133] (stride 133: column
// reads land 2-way banks = free per m136). Reads: ushort8 (16 B/lane, 256-B
// contiguous runs). Writes: 2x float4 per task (32 B/lane, 256-B runs).
// ---------------------------------------------------------------------------
__global__ __launch_bounds__(256) void transpose_out(const unsigned short* __restrict__ ws,
                                                     const float* __restrict__ bias,
                                                     float* __restrict__ out) {
    __shared__ float tile[64][133];
    __shared__ float bsl[64];
    const int o  = blockIdx.x >> 4;        // 0..63
    const int pt = blockIdx.x & 15;        // 16 pos-tiles
    const int p0 = pt * 64;
    const int t  = threadIdx.x;

    if (t < 16)
        *(float4*)&bsl[t * 4] = *(const float4*)(bias + (size_t)o * NPOS + p0 + t * 4);

    // phase 1: 64 pos-rows x 16 chunks of 8 b  (ushort8 loads)
#pragma unroll
    for (int it = 0; it < 4; ++it) {
        const int task = it * 256 + t;
        const int pr = task >> 4;          // pos row 0..63
        const int cb = task & 15;          // 8-b chunk
        const u16x8 v = *(const u16x8*)(ws + (size_t)(p0 + pr) * BO + o * B_ + cb * 8);
#pragma unroll
        for (int u = 0; u < 8; ++u)
            tile[pr][cb * 8 + u] = bf2f(v[u]);
    }
    __syncthreads();

    // phase 2: 128 b x 8 pos-chunks; column reads + bias + float4 stores
    const int l  = t & 63;
    const int wv = t >> 6;
    const int pch = l & 7;                 // pos-chunk (8 pos)
    const int bl  = l >> 3;                // 0..7
#pragma unroll
    for (int it = 0; it < 4; ++it) {
        const int b = it * 32 + wv * 8 + bl;
        float r[8];
#pragma unroll
        for (int u = 0; u < 8; ++u)
            r[u] = tile[pch * 8 + u][b] + bsl[pch * 8 + u];
        float* op = out + ((size_t)b * O_ + o) * NPOS + p0 + pch * 8;
        float4 lo = {r[0], r[1], r[2], r[3]};
        float4 hi = {r[4], r[5], r[6], r[7]};
        *(float4*)op       = lo;
        *(float4*)(op + 4) = hi;
    }
}

// ---------------------------------------------------------------------------
extern "C" void kernel_launch(void* const* d_in, const int* in_sizes, int n_in,
                              void* d_out, int out_size, void* d_ws, size_t ws_size,
                              hipStream_t stream) {
    const float* x      = (const float*)d_in[0];
    const float* weight = (const float*)d_in[1];
    const float* bias   = (const float*)d_in[2];
    float* out          = (float*)d_out;

    const size_t WSB = (size_t)NPOS * BO * sizeof(unsigned short);        // 16,777,216
    const size_t X2B = (size_t)H_ * H_ * BC * sizeof(unsigned short);     //  9,469,952

    if (ws_size >= WSB + X2B) {
        unsigned short* wsout = (unsigned short*)d_ws;
        unsigned short* x2 = (unsigned short*)((char*)d_ws + WSB);
        repack_x<<<64 * 17, 256, 0, stream>>>(x, x2);
        lc_fused<<<1024, 256, 0, stream>>>(x2, weight, wsout);
        transpose_out<<<64 * 16, 256, 0, stream>>>(wsout, bias, out);
    } else {
        lc_fallback<<<NPOS, 256, 0, stream>>>(x, weight, bias, out);
    }
}

// Round 2
// 156.668 us; speedup vs baseline: 1.0513x; 1.0418x over previous
//
#include <hip/hip_runtime.h>
#include <cstdint>
#include <cstddef>

// Problem constants
#define B_    128   // batch
#define C_    32    // in channels
#define O_    64    // out channels
#define H_    34    // input H=W (34 = 32+2)
#define NPOS  1024  // 32*32 spatial positions
#define K9    9     // 3x3 taps
#define BC    (B_ * C_)   // 4096
#define BO    (B_ * O_)   // 8192

typedef __bf16 v8bf __attribute__((ext_vector_type(8)));
typedef float  v4f  __attribute__((ext_vector_type(4)));
typedef float  f4a  __attribute__((ext_vector_type(4)));              // 16-B aligned float4

__device__ __forceinline__ unsigned short f2bf(float f) {
    union { float f; unsigned int u; } v; v.f = f;
    unsigned int u = v.u;
    return (unsigned short)((u + 0x7FFFu + ((u >> 16) & 1u)) >> 16);
}

// ---------------------------------------------------------------------------
// Pass 1: repack x (fp32 [b][c][34][34]) -> x2 (bf16 [h][w][b][c]).
// Block = (b-pair, h-pair); 272-B contiguous reads per (b,c), float2 loads,
// transposed LDS tile, ushort2 stores.  [unchanged from last round]
// ---------------------------------------------------------------------------
__global__ __launch_bounds__(256) void repack_x(const float* __restrict__ x,
                                                unsigned short* __restrict__ x2) {
    const int bq = blockIdx.x / 17;      // b-pair 0..63
    const int hp = blockIdx.x % 17;      // h-pair 0..16
    const int b0 = bq * 2;
    const int h0 = hp * 2;
    __shared__ unsigned short tile[2][H_][66];   // [hh][w][bb*32+c] (+2 pad)
    const int t = threadIdx.x;

    for (int e = t; e < 2176; e += 256) {
        const int bb  = e / 1088;
        const int rem = e % 1088;
        const int c   = rem / 34;
        const int wp  = rem % 34;        // float2 index within the 68-float run
        const float2 v = *(const float2*)(x +
            ((size_t)((b0 + bb) * C_ + c) * H_ + h0) * H_ + wp * 2);
        const int hh = (wp >= 17) ? 1 : 0;
        const int w  = wp * 2 - hh * 34;
        const int idx = bb * 32 + c;
        tile[hh][w][idx]     = f2bf(v.x);
        tile[hh][w + 1][idx] = f2bf(v.y);
    }
    __syncthreads();

    for (int e = t; e < 2176; e += 256) {
        const int hh  = e / 1088;
        const int rem = e % 1088;
        const int w   = rem >> 5;
        const int i2  = rem & 31;
        ushort2 pk;
        pk.x = tile[hh][w][i2 * 2];
        pk.y = tile[hh][w][i2 * 2 + 1];
        *(ushort2*)(x2 + (size_t)((h0 + hh) * H_ + w) * BC + bq * 64 + i2 * 2) = pk;
    }
}

// ---------------------------------------------------------------------------
// Main (v3, fully fused): block = (i, j-octet of 8, o-quarter of 16).
// 512 blocks; LDS Wl = 72 rows x 512 p (bf16, XOR-swizzled) = 73,728 B
//   element (d=jj*9+tap, pl=o_l*32+c) at  d*512 + ((pl>>3)^((d>>2)&7))*8 + (pl&7)
// Staging: pl-quad tasks -> 4x dwordx4 global + 4x ushort4 LDS writes.
// Chunked XCD map: lb = (bid&7)*64 + (bid>>3); lb = i*16 + jq*4 + oq, so each
// XCD owns 4 consecutive i (all jq,oq) -> x2 rows (~1.6 MB) and the 1152-B
// weight pos-rows are L2-local; out 128-B lines (32 pos of one i) stay on
// one XCD.
// Epilogue: direct fp32 out[b][o][pos] + bias — each thread owns 8
// consecutive pos per (b,o): 32-B aligned 32-B runs (one HBM sector, full
// write efficiency). No ws tensor, no transpose kernel.
// ---------------------------------------------------------------------------
__global__ __launch_bounds__(256, 2) void lc_fused2(const unsigned short* __restrict__ x2,
                                                    const float* __restrict__ weight,
                                                    const float* __restrict__ bias,
                                                    float* __restrict__ out) {
    __shared__ __align__(16) unsigned short Wl[72 * 512];  // 73,728 B

    const int bid = blockIdx.x;
    const int lb  = (bid & 7) * 64 + (bid >> 3);   // bijective (512 % 8 == 0)
    const int i   = lb >> 4;           // 0..31
    const int jq  = (lb >> 2) & 3;     // 0..3  (8-j octet)
    const int oq  = lb & 3;            // 0..3  (16-o quarter)
    const int j0  = jq * 8;
    const int o0  = oq * 16;
    const int posbase = i * 32 + j0;   // multiple of 8 -> 32-B aligned out runs
    const int t = threadIdx.x;

    // ---- stage weights: 512 p x 72 floats (contiguous per p) ----
    // tasks: 128 pl-quads x 18 dwordx4 = 2304 = 9 iters x 256 threads
    const float* wbase = weight + ((size_t)(o0 * C_) * NPOS + posbase) * K9;
#pragma unroll
    for (int r = 0; r < 9; ++r) {
        const int idx = r * 256 + t;       // 0..2303
        const int plq = idx / 18;          // pl-quad 0..127
        const int d4  = idx % 18;          // dwordx4 index 0..17
        f4a v0 = *(const f4a*)(wbase + (size_t)(plq * 4 + 0) * (NPOS * K9) + d4 * 4);
        f4a v1 = *(const f4a*)(wbase + (size_t)(plq * 4 + 1) * (NPOS * K9) + d4 * 4);
        f4a v2 = *(const f4a*)(wbase + (size_t)(plq * 4 + 2) * (NPOS * K9) + d4 * 4);
        f4a v3 = *(const f4a*)(wbase + (size_t)(plq * 4 + 3) * (NPOS * K9) + d4 * 4);
        // col(pl) = ((pl>>3)^(d&7))*8 + (pl&7); pl = plq*4+pp -> 4 consecutive
        const int colbase = (((plq >> 1) ^ (d4 & 7)) * 8) + (plq & 1) * 4;
#pragma unroll
        for (int u = 0; u < 4; ++u) {
            ushort4 pk;
            pk.x = f2bf(v0[u]);
            pk.y = f2bf(v1[u]);
            pk.z = f2bf(v2[u]);
            pk.w = f2bf(v3[u]);
            *(ushort4*)&Wl[(d4 * 4 + u) * 512 + colbase] = pk;
        }
    }
    __syncthreads();

    const int wv = t >> 6;      // wave -> b-band [wv*32, wv*32+32)
    const int l  = t & 63;
    const int lm = l & 15;      // o_local (B n-index) / A m-index
    const int q  = l >> 4;

    v4f acc[8][2];              // [jj][mt]
#pragma unroll
    for (int a = 0; a < 8; ++a)
#pragma unroll
        for (int m = 0; m < 2; ++m) acc[a][m] = (v4f){0.f, 0.f, 0.f, 0.f};

#pragma unroll
    for (int kh = 0; kh < 3; ++kh) {
        // load the 10 distinct x2 row-fragments for this kh once
        v8bf ax[10][2];
        const int rowbase = (i + kh) * H_ + j0;
#pragma unroll
        for (int w6 = 0; w6 < 10; ++w6) {
            const unsigned short* xrow = x2 + (size_t)(rowbase + w6) * BC;
            ax[w6][0] = *(const v8bf*)(xrow + (wv * 32 + lm) * C_ + q * 8);
            ax[w6][1] = *(const v8bf*)(xrow + (wv * 32 + 16 + lm) * C_ + q * 8);
        }
#pragma unroll
        for (int kw = 0; kw < 3; ++kw) {
            const int tap = kh * 3 + kw;
#pragma unroll
            for (int jj = 0; jj < 8; ++jj) {
                const int jk = jj * K9 + tap;
                const int g  = ((lm * 4 + q) ^ ((jk >> 2) & 7)) * 8;
                const v8bf bfr = *(const v8bf*)&Wl[jk * 512 + g];
                acc[jj][0] = __builtin_amdgcn_mfma_f32_16x16x32_bf16(
                    ax[kw + jj][0], bfr, acc[jj][0], 0, 0, 0);
                acc[jj][1] = __builtin_amdgcn_mfma_f32_16x16x32_bf16(
                    ax[kw + jj][1], bfr, acc[jj][1], 0, 0, 0);
            }
        }
    }

    // ---- epilogue: fp32 out + bias; 32-B runs per (b,o) ----
    // D layout: col = lane&15 = o_local, row = q*4 + reg = b_local within tile
    const float* bp = bias + (size_t)(o0 + lm) * NPOS + posbase;
    const f4a bv0 = *(const f4a*)bp;
    const f4a bv1 = *(const f4a*)(bp + 4);
#pragma unroll
    for (int mt = 0; mt < 2; ++mt) {
#pragma unroll
        for (int r2 = 0; r2 < 4; ++r2) {
            const int b = wv * 32 + mt * 16 + q * 4 + r2;
            float* op = out + ((size_t)b * O_ + (o0 + lm)) * NPOS + posbase;
            f4a lo = {acc[0][mt][r2] + bv0[0], acc[1][mt][r2] + bv0[1],
                      acc[2][mt][r2] + bv0[2], acc[3][mt][r2] + bv0[3]};
            f4a hi = {acc[4][mt][r2] + bv1[0], acc[5][mt][r2] + bv1[1],
                      acc[6][mt][r2] + bv1[2], acc[7][mt][r2] + bv1[3]};
            *(f4a*)op       = lo;
            *(f4a*)(op + 4) = hi;
        }
    }
}

// ---------------------------------------------------------------------------
// Fallback (no workspace): per-pos kernel gathering straight from fp32.
// ---------------------------------------------------------------------------
__global__ __launch_bounds__(256) void lc_fallback(const float* __restrict__ x,
                                                   const float* __restrict__ weight,
                                                   const float* __restrict__ bias,
                                                   float* __restrict__ out) {
    const int pos = blockIdx.x;
    const int i = pos >> 5, j = pos & 31;
    const int t  = threadIdx.x;
    const int wv = t >> 6;
    const int l  = t & 63;
    const int lm = l & 15;
    const int q  = l >> 4;

    float bv[4];
#pragma unroll
    for (int nt = 0; nt < 4; ++nt)
        bv[nt] = bias[(size_t)(nt * 16 + lm) * NPOS + pos];

    v4f acc[2][4];
#pragma unroll
    for (int a = 0; a < 2; ++a)
#pragma unroll
        for (int n = 0; n < 4; ++n) acc[a][n] = (v4f){0.f, 0.f, 0.f, 0.f};

    for (int k = 0; k < K9; ++k) {
        const int kh = k / 3, kw = k % 3;
        v8bf af[2], bfr[4];
#pragma unroll
        for (int mt = 0; mt < 2; ++mt) {
            const int b = wv * 32 + mt * 16 + lm;
            union { v8bf v; unsigned short s[8]; } u;
#pragma unroll
            for (int cc = 0; cc < 8; ++cc)
                u.s[cc] = f2bf(x[(((size_t)b * C_ + q * 8 + cc) * H_ + (i + kh)) * H_ + (j + kw)]);
            af[mt] = u.v;
        }
#pragma unroll
        for (int nt = 0; nt < 4; ++nt) {
            union { v8bf v; unsigned short s[8]; } u;
#pragma unroll
            for (int cc = 0; cc < 8; ++cc) {
                const int p = (nt * 16 + lm) * C_ + q * 8 + cc;
                u.s[cc] = f2bf(weight[((size_t)p * NPOS + pos) * K9 + k]);
            }
            bfr[nt] = u.v;
        }
#pragma unroll
        for (int mt = 0; mt < 2; ++mt)
#pragma unroll
            for (int nt = 0; nt < 4; ++nt)
                acc[mt][nt] = __builtin_amdgcn_mfma_f32_16x16x32_bf16(
                    af[mt], bfr[nt], acc[mt][nt], 0, 0, 0);
    }
#pragma unroll
    for (int mt = 0; mt < 2; ++mt)
#pragma unroll
        for (int nt = 0; nt < 4; ++nt) {
            const int o = nt * 16 + lm;
#pragma unroll
            for (int r = 0; r < 4; ++r) {
                const int b = wv * 32 + mt * 16 + q * 4 + r;
                out[(size_t)(b * O_ + o) * NPOS + pos] = acc[mt][nt][r] + bv[nt];
            }
        }
}

// ---------------------------------------------------------------------------
extern "C" void kernel_launch(void* const* d_in, const int* in_sizes, int n_in,
                              void* d_out, int out_size, void* d_ws, size_t ws_size,
                              hipStream_t stream) {
    const float* x      = (const float*)d_in[0];
    const float* weight = (const float*)d_in[1];
    const float* bias   = (const float*)d_in[2];
    float* out          = (float*)d_out;

    const size_t X2B = (size_t)H_ * H_ * BC * sizeof(unsigned short);     // 9,469,952

    if (ws_size >= X2B) {
        unsigned short* x2 = (unsigned short*)d_ws;
        repack_x<<<64 * 17, 256, 0, stream>>>(x, x2);
        lc_fused2<<<512, 256, 0, stream>>>(x2, weight, bias, out);
    } else {
        lc_fallback<<<NPOS, 256, 0, stream>>>(x, weight, bias, out);
    }
}